// Round 7
// baseline (367.730 us; speedup 1.0000x reference)
//
#include <hip/hip_runtime.h>

#define D_ 1024
#define H_ 16
#define HD_ 64
#define DFF_ 4096
#define B_ 2
#define S_ 2048
#define MTOK 4096   // B_*S_

typedef unsigned short u16;
typedef short bf16x8 __attribute__((ext_vector_type(8)));
typedef float f32x4 __attribute__((ext_vector_type(4)));

__device__ __forceinline__ u16 f2bf(float f) {
    union { float f; unsigned u; } v; v.f = f;
    return (u16)((v.u + 0x7fffu + ((v.u >> 16) & 1u)) >> 16);
}
// cheap round-half-up bf16 (for P matrix only)
__device__ __forceinline__ u16 f2bf_ru(float f) {
    union { float f; unsigned u; } v; v.f = f;
    return (u16)((v.u + 0x8000u) >> 16);
}

// async global->LDS, 16B per lane. LDS dest = wave-uniform base + lane*16.
__device__ __forceinline__ void gload16(const void* g, void* l) {
    __builtin_amdgcn_global_load_lds(
        (const __attribute__((address_space(1))) unsigned int*)g,
        (__attribute__((address_space(3))) unsigned int*)l, 16, 0, 0);
}

// ---------------- merged transpose + cast: all 6 weights -------------------
__global__ __launch_bounds__(256) void transpose_all_kernel(
    const float* __restrict__ Wq, const float* __restrict__ Wk,
    const float* __restrict__ Wv, const float* __restrict__ Wo,
    const float* __restrict__ W1, const float* __restrict__ W2,
    u16* __restrict__ bQKV, u16* __restrict__ bWo,
    u16* __restrict__ bW1, u16* __restrict__ bW2) {
    int b = blockIdx.x;
    const float* W; u16* Wt; int K, N, nt, kt;
    if (b < 4096) {          // Wq/Wk/Wv/Wo: 1024 tiles each
        int w = b >> 10, t = b & 1023;
        K = 1024; N = 1024; nt = t & 31; kt = t >> 5;
        W = (w == 0) ? Wq : (w == 1) ? Wk : (w == 2) ? Wv : Wo;
        Wt = (w < 3) ? (bQKV + (size_t)w * 1048576u) : bWo;
    } else if (b < 8192) {   // W1: K=1024, N=4096
        int t = b - 4096;
        K = 1024; N = 4096; nt = t & 127; kt = t >> 7;
        W = W1; Wt = bW1;
    } else {                 // W2: K=4096, N=1024
        int t = b - 8192;
        K = 4096; N = 1024; nt = t & 31; kt = t >> 5;
        W = W2; Wt = bW2;
    }
    __shared__ float tl[32][33];
    int n0 = nt * 32, k0 = kt * 32;
    int tx = threadIdx.x, ty = threadIdx.y;   // 32 x 8
#pragma unroll
    for (int i = 0; i < 4; i++)
        tl[ty + i * 8][tx] = W[(size_t)(k0 + ty + i * 8) * N + n0 + tx];
    __syncthreads();
#pragma unroll
    for (int i = 0; i < 4; i++)
        Wt[(size_t)(n0 + ty + i * 8) * K + k0 + tx] = f2bf(tl[tx][ty + i * 8]);
}

// ---------------- LayerNorm (ddof=1) fp32 -> bf16 --------------------------
__global__ __launch_bounds__(256) void ln_kernel(
    const float* __restrict__ x, const float* __restrict__ gamma,
    const float* __restrict__ beta, u16* __restrict__ out) {
    int row = blockIdx.x, tid = threadIdx.x;
    int wave = tid >> 6, lane = tid & 63;
    const float4* xr = (const float4*)(x + (size_t)row * D_);
    float4 v = xr[tid];
    float s = v.x + v.y + v.z + v.w;
#pragma unroll
    for (int off = 1; off < 64; off <<= 1) s += __shfl_xor(s, off, 64);
    __shared__ float p1[4], p2[4];
    if (lane == 0) p1[wave] = s;
    __syncthreads();
    float mean = (p1[0] + p1[1] + p1[2] + p1[3]) * (1.0f / D_);
    float4 d = {v.x - mean, v.y - mean, v.z - mean, v.w - mean};
    float sq = d.x * d.x + d.y * d.y + d.z * d.z + d.w * d.w;
#pragma unroll
    for (int off = 1; off < 64; off <<= 1) sq += __shfl_xor(sq, off, 64);
    if (lane == 0) p2[wave] = sq;
    __syncthreads();
    float var = (p2[0] + p2[1] + p2[2] + p2[3]) * (1.0f / (D_ - 1));
    float rstd = rsqrtf(var + 1e-12f);
    float4 gv = ((const float4*)gamma)[tid];
    float4 bv = ((const float4*)beta)[tid];
    u16* orow = out + (size_t)row * D_ + tid * 4;
    orow[0] = f2bf(gv.x * d.x * rstd + bv.x);
    orow[1] = f2bf(gv.y * d.y * rstd + bv.y);
    orow[2] = f2bf(gv.z * d.z * rstd + bv.z);
    orow[3] = f2bf(gv.w * d.w * rstd + bv.w);
}

constexpr int EPI_QKV = 0, EPI_O = 3, EPI_G = 4, EPI_R = 5;

// ---------------- epilogue helper ------------------------------------------
template <int EPI>
__device__ __forceinline__ void epi_store(
    float accv, int m, int n, const float* bias, const float* bias2,
    const float* bias3, const float* resid, void* Cout) {
    if constexpr (EPI == EPI_QKV) {
        int which = n >> 10, d = n & 1023;
        const float* bp = (which == 0) ? bias : (which == 1) ? bias2 : bias3;
        float cval = accv + bp[d];
        int b = m >> 11, s = m & 2047, h = d >> 6, hd = d & 63;
        u16* qkv = (u16*)Cout;
        if (which == 0)
            qkv[((size_t)(b * H_ + h) * S_ + s) * HD_ + hd] = f2bf(cval);
        else if (which == 1)
            qkv[4194304u + ((size_t)(b * H_ + h) * S_ + s) * HD_ + hd] = f2bf(cval);
        else
            qkv[8388608u + ((size_t)(b * H_ + h) * HD_ + hd) * S_ + s] = f2bf(cval);
    } else if constexpr (EPI == EPI_O) {
        float cval = accv + bias[n];
        ((float*)Cout)[(size_t)m * D_ + n] = resid[(size_t)m * D_ + n] + cval;
    } else if constexpr (EPI == EPI_G) {
        float cval = accv + bias[n];
        float u = 0.7978845608028654f * (cval + 0.044715f * cval * cval * cval);
        float t = 1.0f - 2.0f / (__expf(2.0f * u) + 1.0f);
        ((u16*)Cout)[(size_t)m * DFF_ + n] = f2bf(0.5f * cval * (1.0f + t));
    } else {  // EPI_R
        float cval = accv + bias[n];
        ((float*)Cout)[(size_t)m * D_ + n] = resid[(size_t)m * D_ + n] + cval;
    }
}

// ---------------- fat GEMM: 256x128 block, wave = 64 rows x 128 cols -------
// 32 MFMA per 12 ds_read_b128 per wave-iter (2.7:1) vs 2:1 in the 128x128
// kernel — attacks the LDS-pipe bound. 3-slot ring, raw barrier, depth 2.
template <int EPI, int KD, int GYB>
__global__ __launch_bounds__(256, 2) void gemm_fat_kernel(
    const u16* __restrict__ A, const u16* __restrict__ Bt,
    const float* __restrict__ bias, const float* __restrict__ bias2,
    const float* __restrict__ bias3, const float* __restrict__ resid,
    void* __restrict__ Cout) {
    __shared__ alignas(16) char Alds[3][16384];   // 256 rows x 32 k
    __shared__ alignas(16) char Blds[3][8192];    // 128 rows x 32 k
    int tid = threadIdx.x;
    int tm = (blockIdx.x & ((1 << GYB) - 1)) * 256;
    int tn = (blockIdx.x >> GYB) * 128;
    int wave = tid >> 6, lane = tid & 63;
    int lcol = lane & 15, quad = lane >> 4;
    f32x4 acc[4][8] = {};

    int l = lane >> 3, p = lane & 7, slog = p ^ l;
    int sro = l * 2 + (slog >> 2), sch = slog & 3;
    const u16* ga = A + (size_t)(tm + wave * 64 + sro) * KD + sch * 8;
    const u16* gb = Bt + (size_t)(tn + wave * 32 + sro) * KD + sch * 8;

    auto stage = [&](int k0, int slot) {
        char* lA = Alds[slot] + wave * 4096;
        char* lB = Blds[slot] + wave * 2048;
        gload16(ga + k0, lA);
        gload16(ga + (size_t)16 * KD + k0, lA + 1024);
        gload16(ga + (size_t)32 * KD + k0, lA + 2048);
        gload16(ga + (size_t)48 * KD + k0, lA + 3072);
        gload16(gb + k0, lB);
        gload16(gb + (size_t)16 * KD + k0, lB + 1024);
    };

    constexpr int NT = KD / 32;
    stage(0, 0);
    stage(32, 1);
    int swz = (lcol >> 1) * 128 + (((((lcol & 1) << 2) | quad) ^ (lcol >> 1)) * 16);
#pragma unroll 1
    for (int kt = 0; kt < NT; kt++) {
        if (kt == NT - 1) {
            asm volatile("s_waitcnt vmcnt(0)" ::: "memory");
        } else {
            asm volatile("s_waitcnt vmcnt(6)" ::: "memory");
        }
        asm volatile("s_barrier" ::: "memory");
        if (kt + 2 < NT) stage((kt + 2) * 32, (kt + 2) % 3);
        int cur = kt % 3;
        bf16x8 af[4], bfr[8];
#pragma unroll
        for (int i = 0; i < 4; i++)
            af[i] = *(const bf16x8*)(Alds[cur] + wave * 4096 + i * 1024 + swz);
#pragma unroll
        for (int j = 0; j < 8; j++)
            bfr[j] = *(const bf16x8*)(Blds[cur] + j * 1024 + swz);
#pragma unroll
        for (int i = 0; i < 4; i++)
#pragma unroll
            for (int j = 0; j < 8; j++)
                acc[i][j] = __builtin_amdgcn_mfma_f32_16x16x32_bf16(
                    af[i], bfr[j], acc[i][j], 0, 0, 0);
    }
#pragma unroll
    for (int i = 0; i < 4; i++)
#pragma unroll
        for (int j = 0; j < 8; j++)
#pragma unroll
            for (int r = 0; r < 4; r++) {
                int m = tm + wave * 64 + i * 16 + quad * 4 + r;
                int n = tn + j * 16 + lcol;
                epi_store<EPI>(acc[i][j][r], m, n, bias, bias2, bias3, resid, Cout);
            }
}

// ---------------- GEMM (128/64-row tiles), 3-slot ring ---------------------
template <int EPI, int KD, int TM, int BK, int GYB>
__global__ __launch_bounds__(256) void gemm_kernel(
    const u16* __restrict__ A, const u16* __restrict__ Bt,
    const float* __restrict__ bias, const float* __restrict__ bias2,
    const float* __restrict__ bias3, const float* __restrict__ resid,
    void* __restrict__ Cout) {
    __shared__ alignas(16) char Alds[3][TM * BK * 2];
    __shared__ alignas(16) char Blds[3][128 * BK * 2];
    int tid = threadIdx.x;
    int tm = (blockIdx.x & ((1 << GYB) - 1)) * TM;
    int tn = (blockIdx.x >> GYB) * 128;
    int wave = tid >> 6, lane = tid & 63;
    int wrow = (wave >> 1) * (TM / 2), wcol = (wave & 1) * 64;
    int lcol = lane & 15, quad = lane >> 4;
    constexpr int NI = TM / 32;
    constexpr int G = (BK == 32) ? 4 : 6;
    f32x4 acc[NI][4] = {};

    const u16 *ga, *gb;
    if constexpr (BK == 32) {
        int l = lane >> 3, p = lane & 7, slog = p ^ l;
        int sro = l * 2 + (slog >> 2), sch = slog & 3;
        ga = A + (size_t)(tm + wave * 16 + sro) * KD + sch * 8;
        gb = Bt + (size_t)(tn + wave * 16 + sro) * KD + sch * 8;
    } else {  // BK == 64 (TM == 64)
        int g = (lane & 7) ^ (lane >> 3);
        ga = A + (size_t)(tm + wave * 16 + (lane >> 3)) * KD + g * 8;
        gb = Bt + (size_t)(tn + wave * 32 + (lane >> 3)) * KD + g * 8;
    }

    auto stage = [&](int k0, int slot) {
        if constexpr (BK == 32) {
            char* lA = Alds[slot] + wave * 1024;
            char* lB = Blds[slot] + wave * 1024;
            gload16(ga + k0, lA);
            gload16(ga + (size_t)64 * KD + k0, lA + 4096);
            gload16(gb + k0, lB);
            gload16(gb + (size_t)64 * KD + k0, lB + 4096);
        } else {
            char* lA = Alds[slot] + wave * 2048;
            gload16(ga + k0, lA);
            gload16(ga + (size_t)8 * KD + k0, lA + 1024);
            char* lB = Blds[slot] + wave * 4096;
            gload16(gb + k0, lB);
            gload16(gb + (size_t)8 * KD + k0, lB + 1024);
            gload16(gb + (size_t)16 * KD + k0, lB + 2048);
            gload16(gb + (size_t)24 * KD + k0, lB + 3072);
        }
    };

    constexpr int NT = KD / BK;
    stage(0, 0);
    stage(BK, 1);
#pragma unroll 1
    for (int kt = 0; kt < NT; kt++) {
        if (kt == NT - 1) {
            asm volatile("s_waitcnt vmcnt(0)" ::: "memory");
        } else if constexpr (G == 4) {
            asm volatile("s_waitcnt vmcnt(4)" ::: "memory");
        } else {
            asm volatile("s_waitcnt vmcnt(6)" ::: "memory");
        }
        asm volatile("s_barrier" ::: "memory");
        if (kt + 2 < NT) stage((kt + 2) * BK, (kt + 2) % 3);
        int cur = kt % 3;
        if constexpr (BK == 32) {
            int swz = (lcol >> 1) * 128 + (((((lcol & 1) << 2) | quad) ^ (lcol >> 1)) * 16);
            bf16x8 af[NI], bfr[4];
#pragma unroll
            for (int i = 0; i < NI; i++)
                af[i] = *(const bf16x8*)(Alds[cur] + wrow * 64 + i * 1024 + swz);
#pragma unroll
            for (int j = 0; j < 4; j++)
                bfr[j] = *(const bf16x8*)(Blds[cur] + wcol * 64 + j * 1024 + swz);
#pragma unroll
            for (int i = 0; i < NI; i++)
#pragma unroll
                for (int j = 0; j < 4; j++)
                    acc[i][j] = __builtin_amdgcn_mfma_f32_16x16x32_bf16(
                        af[i], bfr[j], acc[i][j], 0, 0, 0);
        } else {
            int koff0 = lcol * 128 + ((quad ^ (lcol & 7)) * 16);
            int koff1 = lcol * 128 + (((4 | quad) ^ (lcol & 7)) * 16);
            bf16x8 af0[NI], af1[NI], bf0[4], bf1[4];
#pragma unroll
            for (int i = 0; i < NI; i++) {
                af0[i] = *(const bf16x8*)(Alds[cur] + (wrow + i * 16) * 128 + koff0);
                af1[i] = *(const bf16x8*)(Alds[cur] + (wrow + i * 16) * 128 + koff1);
            }
#pragma unroll
            for (int j = 0; j < 4; j++) {
                bf0[j] = *(const bf16x8*)(Blds[cur] + (wcol + j * 16) * 128 + koff0);
                bf1[j] = *(const bf16x8*)(Blds[cur] + (wcol + j * 16) * 128 + koff1);
            }
#pragma unroll
            for (int i = 0; i < NI; i++)
#pragma unroll
                for (int j = 0; j < 4; j++)
                    acc[i][j] = __builtin_amdgcn_mfma_f32_16x16x32_bf16(
                        af0[i], bf0[j], acc[i][j], 0, 0, 0);
#pragma unroll
            for (int i = 0; i < NI; i++)
#pragma unroll
                for (int j = 0; j < 4; j++)
                    acc[i][j] = __builtin_amdgcn_mfma_f32_16x16x32_bf16(
                        af1[i], bf1[j], acc[i][j], 0, 0, 0);
        }
    }
#pragma unroll
    for (int i = 0; i < NI; i++)
#pragma unroll
        for (int j = 0; j < 4; j++)
#pragma unroll
            for (int r = 0; r < 4; r++) {
                int m = tm + wrow + i * 16 + quad * 4 + r;
                int n = tn + wcol + j * 16 + lcol;
                epi_store<EPI>(acc[i][j][r], m, n, bias, bias2, bias3, resid, Cout);
            }
}

// ---------------- Flash attention (causal), paired q-tiles -----------------
__global__ __launch_bounds__(256) void attn_kernel(
    const u16* __restrict__ q, const u16* __restrict__ k,
    const u16* __restrict__ v, u16* __restrict__ ctx) {
    __shared__ alignas(16) u16 klds[3][64 * 64];
    __shared__ alignas(16) u16 vlds[3][64 * 64];
    __shared__ alignas(16) u16 plds[4][16 * 64];
    int tid = threadIdx.x, wave = tid >> 6, lane = tid & 63;
    int quad = lane >> 4, lcol = lane & 15;
    int bh = blockIdx.x & 31, pairi = blockIdx.x >> 5;
    const u16* qbase = q + (size_t)bh * S_ * HD_;
    const u16* kbase = k + (size_t)bh * S_ * HD_;
    const u16* vbase = v + (size_t)bh * HD_ * S_;
    int g = (lane & 7) ^ (lane >> 3);
    int srow = wave * 16 + (lane >> 3);
    const u16* kp = kbase + (size_t)srow * HD_ + g * 8;
    const u16* vp = vbase + (size_t)srow * S_ + g * 8;
    char* pbase = (char*)plds + wave * 2048;
    int koff0 = lcol * 128 + ((quad ^ (lcol & 7)) * 16);
    int koff1 = lcol * 128 + (((4 | quad) ^ (lcol & 7)) * 16);
    int b = bh >> 4, h = bh & 15;
    auto stage = [&](int kt, int slot) {
        int k0 = kt * 64;
        char* kd = (char*)klds[slot] + wave * 2048;
        char* vd = (char*)vlds[slot] + wave * 2048;
        gload16(kp + (size_t)k0 * HD_, kd);
        gload16(kp + (size_t)(k0 + 8) * HD_, kd + 1024);
        gload16(vp + k0, vd);
        gload16(vp + 8 * S_ + k0, vd + 1024);
    };
#pragma unroll 1
    for (int half = 0; half < 2; half++) {
        int qt = half ? (31 - pairi) : pairi;
        int qr = qt * 64 + wave * 16;
        bf16x8 aq0 = *(const bf16x8*)(qbase + (size_t)(qr + lcol) * HD_ + quad * 8);
        bf16x8 aq1 = *(const bf16x8*)(qbase + (size_t)(qr + lcol) * HD_ + 32 + quad * 8);
        f32x4 co[4] = {};
        float li[4] = {0.0f, 0.0f, 0.0f, 0.0f};
        __syncthreads();   // protect slots from previous half's readers
        stage(0, 0);
        if (qt >= 1) stage(1, 1);
#pragma unroll 1
        for (int kt = 0; kt <= qt; kt++) {
            if (kt == qt) {
                asm volatile("s_waitcnt vmcnt(0)" ::: "memory");
            } else {
                asm volatile("s_waitcnt vmcnt(4)" ::: "memory");
            }
            asm volatile("s_barrier" ::: "memory");
            if (kt + 2 <= qt) stage(kt + 2, (kt + 2) % 3);
            const u16* kl = klds[kt % 3];
            const u16* vl = vlds[kt % 3];
            f32x4 cs[4] = {};
#pragma unroll
            for (int j = 0; j < 4; j++) {
                bf16x8 bk = *(const bf16x8*)((char*)kl + j * 2048 + koff0);
                cs[j] = __builtin_amdgcn_mfma_f32_16x16x32_bf16(aq0, bk, cs[j], 0, 0, 0);
            }
#pragma unroll
            for (int j = 0; j < 4; j++) {
                bf16x8 bk = *(const bf16x8*)((char*)kl + j * 2048 + koff1);
                cs[j] = __builtin_amdgcn_mfma_f32_16x16x32_bf16(aq1, bk, cs[j], 0, 0, 0);
            }
            bool diag = (kt == qt);
#pragma unroll
            for (int r = 0; r < 4; r++) {
                int rr = quad * 4 + r;
                float p[4], ls = 0.0f;
#pragma unroll
                for (int j = 0; j < 4; j++) {
                    float sv = cs[j][r];
                    if (diag && (j * 16 + lcol > wave * 16 + rr)) sv = -1e38f;
                    p[j] = exp2f(sv * 0.18033688011112042f);   // exp(s/8)
                    ls += p[j];
                }
                li[r] += ls;
                int pr = rr * 128 + (lcol & 7) * 2;
#pragma unroll
                for (int j = 0; j < 4; j++)
                    *(u16*)(pbase + pr + (((j * 2 + (lcol >> 3)) ^ (rr & 7)) * 16)) = f2bf_ru(p[j]);
            }
            {
                bf16x8 ap0 = *(const bf16x8*)(pbase + koff0);
                bf16x8 ap1 = *(const bf16x8*)(pbase + koff1);
#pragma unroll
                for (int j = 0; j < 4; j++) {
                    bf16x8 bv0 = *(const bf16x8*)((char*)vl + j * 2048 + koff0);
                    co[j] = __builtin_amdgcn_mfma_f32_16x16x32_bf16(ap0, bv0, co[j], 0, 0, 0);
                }
#pragma unroll
                for (int j = 0; j < 4; j++) {
                    bf16x8 bv1 = *(const bf16x8*)((char*)vl + j * 2048 + koff1);
                    co[j] = __builtin_amdgcn_mfma_f32_16x16x32_bf16(ap1, bv1, co[j], 0, 0, 0);
                }
            }
        }
#pragma unroll
        for (int r = 0; r < 4; r++) {
            float l = li[r];
            l += __shfl_xor(l, 1);
            l += __shfl_xor(l, 2);
            l += __shfl_xor(l, 4);
            l += __shfl_xor(l, 8);
            float inv = 1.0f / l;
            int row = qr + quad * 4 + r;
            size_t base = ((size_t)(b * S_ + row)) * D_ + h * HD_;
#pragma unroll
            for (int j = 0; j < 4; j++)
                ctx[base + j * 16 + lcol] = f2bf(co[j][r] * inv);
        }
    }
}

// ---------------- launcher -------------------------------------------------
extern "C" void kernel_launch(void* const* d_in, const int* in_sizes, int n_in,
                              void* d_out, int out_size, void* d_ws, size_t ws_size,
                              hipStream_t stream) {
    const float* x  = (const float*)d_in[0];
    const float* Wq = (const float*)d_in[1];
    const float* bq = (const float*)d_in[2];
    const float* Wk = (const float*)d_in[3];
    const float* bk = (const float*)d_in[4];
    const float* Wv = (const float*)d_in[5];
    const float* bv = (const float*)d_in[6];
    const float* Wo = (const float*)d_in[7];
    const float* bo = (const float*)d_in[8];
    const float* W1 = (const float*)d_in[9];
    const float* b1 = (const float*)d_in[10];
    const float* W2 = (const float*)d_in[11];
    const float* b2 = (const float*)d_in[12];
    const float* g1 = (const float*)d_in[13];
    const float* s1 = (const float*)d_in[14];
    const float* g2 = (const float*)d_in[15];
    const float* s2 = (const float*)d_in[16];

    char* ws = (char*)d_ws;
    const size_t MB = 1024 * 1024;
    u16*   bWqkv = (u16*)(ws + 0 * MB);    // [3072][1024] bf16 (q rows, k, v)
    u16*   bWo   = (u16*)(ws + 6 * MB);    // [1024][1024]
    u16*   bW1   = (u16*)(ws + 8 * MB);    // [4096][1024]
    u16*   bW2   = (u16*)(ws + 16 * MB);   // [1024][4096]
    u16*   hbuf  = (u16*)(ws + 24 * MB);   // [4096][1024] bf16
    u16*   qbuf  = (u16*)(ws + 32 * MB);   // q[32][2048][64], k at +4M, v at +8M elems
    u16*   ctxb  = (u16*)(ws + 56 * MB);   // [4096][1024] bf16
    float* x1    = (float*)(ws + 64 * MB); // [4096][1024] fp32
    u16*   ffb   = (u16*)(ws + 80 * MB);   // [4096][4096] bf16

    transpose_all_kernel<<<12288, dim3(32, 8), 0, stream>>>(
        Wq, Wk, Wv, Wo, W1, W2, bWqkv, bWo, bW1, bW2);

    ln_kernel<<<MTOK, 256, 0, stream>>>(x, g1, s1, hbuf);

    // fused QKV projection: N=3072, fat tile 256x128 -> 16 x 24 = 384 blocks
    gemm_fat_kernel<EPI_QKV, D_, 4><<<384, 256, 0, stream>>>(
        hbuf, bWqkv, bq, bk, bv, nullptr, qbuf);

    attn_kernel<<<512, 256, 0, stream>>>(
        qbuf, qbuf + 4194304u, qbuf + 8388608u, ctxb);

    // O projection (N=1024): TM=64/BK=64, GY=64 -> 512 blocks
    gemm_kernel<EPI_O, D_, 64, 64, 6><<<512, 256, 0, stream>>>(
        ctxb, bWo, bo, nullptr, nullptr, x, x1);

    ln_kernel<<<MTOK, 256, 0, stream>>>(x1, g2, s2, hbuf);

    // FF1 (N=4096): fat tile 256x128 -> 16 x 32 = 512 blocks
    gemm_fat_kernel<EPI_G, D_, 4><<<512, 256, 0, stream>>>(
        hbuf, bW1, b1, nullptr, nullptr, nullptr, ffb);

    // FF2 (N=1024, K=4096): TM=64/BK=64, GY=64 -> 512 blocks
    gemm_kernel<EPI_R, DFF_, 64, 64, 6><<<512, 256, 0, stream>>>(
        ffb, bW2, b2, nullptr, nullptr, x1, (float*)d_out);
}